// Round 1
// baseline (202.412 us; speedup 1.0000x reference)
//
#include <hip/hip_runtime.h>
#include <math.h>

#define TPB 512
#define CAP 4096   // LDS candidate list capacity (16 KiB)

// ---------------- boost precompute: boost = f32(exp(f64(1.5f*(0.02f - dc)))) ----
__global__ void boost_kernel(const float* __restrict__ dc, float* __restrict__ boost, int n) {
    int i = blockIdx.x * blockDim.x + threadIdx.x;
    if (i < n) {
        float a = 1.5f * (0.02f - dc[i]);   // exact f32 arithmetic, same as reference
        boost[i] = (float)exp((double)a);   // correctly-rounded f32 exp via f64
    }
}

// monotone float -> uint32 key (no NaNs in input)
__device__ __forceinline__ unsigned fkey(float f) {
    unsigned u = __float_as_uint(f);
    return (u & 0x80000000u) ? ~u : (u | 0x80000000u);
}

__global__ __launch_bounds__(TPB, 4)
void kwta_kernel(const float* __restrict__ x,
                 const float* __restrict__ boost,   // may be null -> compute inline
                 const float* __restrict__ dc,
                 float* __restrict__ out,
                 int n, int k) {
    const int row  = blockIdx.x;
    const int tid  = threadIdx.x;
    const int lane = tid & 63;

    __shared__ unsigned s_list[CAP];
    __shared__ int s_cnt[4];
    __shared__ int s_nc;

    if (tid < 4) s_cnt[tid] = 0;
    if (tid == 0) s_nc = 0;

    // ---- load row, build keys in registers (n == 16384, 32 elems/thread) ----
    const float4* x4 = (const float4*)(x + (size_t)row * n);
    unsigned key[32];
    if (boost) {
        const float4* b4 = (const float4*)boost;
        #pragma unroll
        for (int i = 0; i < 8; ++i) {
            float4 xv = x4[tid + i * TPB];
            float4 bv = b4[tid + i * TPB];
            key[4*i+0] = fkey(xv.x * bv.x);
            key[4*i+1] = fkey(xv.y * bv.y);
            key[4*i+2] = fkey(xv.z * bv.z);
            key[4*i+3] = fkey(xv.w * bv.w);
        }
    } else {
        const float4* d4 = (const float4*)dc;
        #pragma unroll
        for (int i = 0; i < 8; ++i) {
            float4 xv = x4[tid + i * TPB];
            float4 dv = d4[tid + i * TPB];
            float bx = (float)exp((double)(1.5f * (0.02f - dv.x)));
            float by = (float)exp((double)(1.5f * (0.02f - dv.y)));
            float bz = (float)exp((double)(1.5f * (0.02f - dv.z)));
            float bw = (float)exp((double)(1.5f * (0.02f - dv.w)));
            key[4*i+0] = fkey(xv.x * bx);
            key[4*i+1] = fkey(xv.y * by);
            key[4*i+2] = fkey(xv.z * bz);
            key[4*i+3] = fkey(xv.w * bw);
        }
    }
    __syncthreads();   // covers s_cnt / s_nc init

    int it = 0;
    unsigned P = 0;

    // block-wide sum with ONE barrier per use (4-slot rotation; slot it+2 zeroed each use)
    auto block_total = [&](int c) -> int {
        #pragma unroll
        for (int off = 32; off; off >>= 1) c += __shfl_down(c, off);
        int s = it & 3;
        if (lane == 0) atomicAdd(&s_cnt[s], c);
        __syncthreads();
        int total = s_cnt[s];
        if (tid == 0) s_cnt[(s + 2) & 3] = 0;
        ++it;
        return total;
    };

    // ---- phase 1: bisect top 10 bits over register-resident keys ----
    for (int b = 31; b >= 22; --b) {
        unsigned C = P | (1u << b);
        int c = 0;
        #pragma unroll
        for (int j = 0; j < 32; ++j) c += (key[j] >= C) ? 1 : 0;
        if (block_total(c) >= k) P = C;
    }

    // ---- phase 2: compact candidates (top 10 bits == P's) into LDS ----
    const unsigned Ptop = P >> 22;
    int hi = 0;
    #pragma unroll
    for (int j = 0; j < 32; ++j) hi += ((key[j] >> 22) > Ptop) ? 1 : 0;

    #pragma unroll
    for (int j = 0; j < 32; ++j) {
        bool e = ((key[j] >> 22) == Ptop);
        unsigned long long m = __ballot(e);
        if (m) {
            int cntm   = (int)__popcll(m);
            int pre    = (int)__popcll(m & ((1ull << lane) - 1ull));
            int leader = __ffsll((long long)m) - 1;
            int base = 0;
            if (lane == leader) base = atomicAdd(&s_nc, cntm);
            base = __shfl(base, leader);
            if (e) {
                int pos = base + pre;
                if (pos < CAP) s_list[pos] = key[j];
            }
        }
    }
    int hi_total = block_total(hi);   // barrier inside also publishes s_nc / s_list
    int nc = s_nc;

    // ---- phase 3: bisect remaining 22 bits ----
    if (nc > 0 && nc <= CAP) {
        int kp = k - hi_total;        // rank within candidate set (>=1 by invariant)
        for (int b = 21; b >= 0; --b) {
            unsigned C = P | (1u << b);
            int c = 0;
            for (int idx = tid; idx < nc; idx += TPB) c += (s_list[idx] >= C) ? 1 : 0;
            if (block_total(c) >= kp) P = C;
        }
    } else {
        // fallback: full-register bisection (correct for any data)
        for (int b = 21; b >= 0; --b) {
            unsigned C = P | (1u << b);
            int c = 0;
            #pragma unroll
            for (int j = 0; j < 32; ++j) c += (key[j] >= C) ? 1 : 0;
            if (block_total(c) >= k) P = C;
        }
    }

    // ---- phase 4: write mask (key >= P  <=>  xb >= threshold) ----
    float4* o4 = (float4*)(out + (size_t)row * n);
    #pragma unroll
    for (int i = 0; i < 8; ++i) {
        float4 o;
        o.x = (key[4*i+0] >= P) ? 1.0f : 0.0f;
        o.y = (key[4*i+1] >= P) ? 1.0f : 0.0f;
        o.z = (key[4*i+2] >= P) ? 1.0f : 0.0f;
        o.w = (key[4*i+3] >= P) ? 1.0f : 0.0f;
        o4[tid + i * TPB] = o;
    }
}

extern "C" void kernel_launch(void* const* d_in, const int* in_sizes, int n_in,
                              void* d_out, int out_size, void* d_ws, size_t ws_size,
                              hipStream_t stream) {
    const float* x  = (const float*)d_in[0];
    const float* dc = (const float*)d_in[1];
    float* out = (float*)d_out;

    int n    = in_sizes[1];             // 16384
    int rows = in_sizes[0] / n;         // 4096
    int k    = (int)llround((double)n * 0.02);
    if (k < 1) k = 1;

    bool use_ws = (ws_size >= (size_t)n * sizeof(float));
    float* boost = use_ws ? (float*)d_ws : nullptr;

    if (use_ws) {
        boost_kernel<<<(n + 255) / 256, 256, 0, stream>>>(dc, boost, n);
    }
    kwta_kernel<<<rows, TPB, 0, stream>>>(x, boost, dc, out, n, k);
}